// Round 8
// baseline (1782.502 us; speedup 1.0000x reference)
//
#include <hip/hip_runtime.h>
#include <hip/hip_fp16.h>

// Problem constants
#define B_   64
#define T_   512
#define I_   128
#define H_   256
#define G4_  1024   // 4*H
#define R_   20
#define DA_  50
#define C_   10

typedef _Float16 half2_t __attribute__((ext_vector_type(2)));

__device__ __forceinline__ float fsigmoid(float x) {
  return __fdividef(1.0f, 1.0f + __expf(-x));
}
__device__ __forceinline__ float ftanh(float x) {
  return 1.0f - __fdividef(2.0f, __expf(2.0f * x) + 1.0f);
}

// ---------------------------------------------------------------------------
// K0: pack W_hh [256][1024] fp32 -> Wq[g][k2] half2 (column-major per gate col)
// ---------------------------------------------------------------------------
__global__ __launch_bounds__(256) void k0_pack(const float* __restrict__ Whh,
                                               half2_t* __restrict__ Wq) {
  int idx = blockIdx.x * 256 + threadIdx.x;   // 0..131071
  int g = idx & 1023, k2 = idx >> 10;
  half2_t h;
  h.x = (_Float16)Whh[(2 * k2) * G4_ + g];
  h.y = (_Float16)Whh[(2 * k2 + 1) * G4_ + g];
  Wq[g * 128 + k2] = h;
}

// ---------------------------------------------------------------------------
// K_init: zero the h-exchange mailboxes (Hx: [2][64][256] u32 = 128 KiB)
// ---------------------------------------------------------------------------
__global__ __launch_bounds__(256) void k_init(unsigned long long* __restrict__ Hx) {
  int i = blockIdx.x * 256 + threadIdx.x;   // 16384 u64 slots = 128 KiB
  Hx[i] = 0ull;
}

// ---------------------------------------------------------------------------
// K1: S = (tanh(x@W1^T + b1))@W2^T + b2, layout S[B,R,T].
// ---------------------------------------------------------------------------
__global__ __launch_bounds__(256) void k1_scores(const float* __restrict__ x,
                                                 const float* __restrict__ W1,
                                                 const float* __restrict__ b1,
                                                 const float* __restrict__ W2,
                                                 const float* __restrict__ b2,
                                                 float* __restrict__ S) {
  __shared__ float xs[64][129];
  __shared__ float w1s[128][64];
  __shared__ float a1s[64][53];
  int blk = blockIdx.x;
  int tid = threadIdx.x;
  int row0 = blk * 64;
  const float4* xv = (const float4*)(x + (size_t)row0 * I_);
#pragma unroll
  for (int ch = 0; ch < 8; ch++) {
    int fidx = ch * 256 + tid;
    int r = fidx >> 5, k4 = (fidx & 31) << 2;
    float4 f = xv[fidx];
    xs[r][k4] = f.x; xs[r][k4 + 1] = f.y; xs[r][k4 + 2] = f.z; xs[r][k4 + 3] = f.w;
  }
  const float4* w1v = (const float4*)W1;
#pragma unroll
  for (int ch = 0; ch < 7; ch++) {
    int fidx = ch * 256 + tid;
    if (fidx < 1600) {
      int d = fidx >> 5, k4 = (fidx & 31) << 2;
      float4 f = w1v[fidx];
      w1s[k4][d] = f.x; w1s[k4 + 1][d] = f.y; w1s[k4 + 2][d] = f.z; w1s[k4 + 3][d] = f.w;
    }
  }
  __syncthreads();
  int ty = tid >> 4, tx = tid & 15;
  float acc[4][4] = {};
#pragma unroll 4
  for (int k = 0; k < I_; k++) {
    float a0 = xs[4 * ty][k], a1 = xs[4 * ty + 1][k];
    float a2 = xs[4 * ty + 2][k], a3 = xs[4 * ty + 3][k];
    float4 bq = *(const float4*)&w1s[k][tx << 2];
    acc[0][0] += a0 * bq.x; acc[0][1] += a0 * bq.y; acc[0][2] += a0 * bq.z; acc[0][3] += a0 * bq.w;
    acc[1][0] += a1 * bq.x; acc[1][1] += a1 * bq.y; acc[1][2] += a1 * bq.z; acc[1][3] += a1 * bq.w;
    acc[2][0] += a2 * bq.x; acc[2][1] += a2 * bq.y; acc[2][2] += a2 * bq.z; acc[2][3] += a2 * bq.w;
    acc[3][0] += a3 * bq.x; acc[3][1] += a3 * bq.y; acc[3][2] += a3 * bq.z; acc[3][3] += a3 * bq.w;
  }
#pragma unroll
  for (int i = 0; i < 4; i++) {
#pragma unroll
    for (int j = 0; j < 4; j++) {
      int col = (tx << 2) + j;
      if (col < DA_) a1s[4 * ty + i][col] = tanhf(acc[i][j] + b1[col]);
    }
  }
  __syncthreads();
  int row = tid & 63, rq = tid >> 6;
  int bt = row0 + row;
  int b = bt >> 9, t = bt & 511;
#pragma unroll
  for (int m = 0; m < 5; m++) {
    int r = rq + (m << 2);
    float acc2 = b2[r];
#pragma unroll 10
    for (int d = 0; d < DA_; d++) acc2 += a1s[row][d] * W2[r * DA_ + d];
    S[((size_t)(b * R_ + r)) * T_ + t] = acc2;
  }
}

// ---------------------------------------------------------------------------
// K2: per (b,r): m = max_t S; E = exp(S-m); invd[t] = 1/cumsum(E)[t]
// ---------------------------------------------------------------------------
__global__ __launch_bounds__(64) void k2_prefix(const float* __restrict__ S,
                                                float* __restrict__ E,
                                                float* __restrict__ invd) {
  int br = blockIdx.x;
  int l = threadIdx.x;
  const float* Sr = S + (size_t)br * T_;
  float v[8];
  float m = -1e30f;
#pragma unroll
  for (int c = 0; c < 8; c++) {
    v[c] = Sr[c * 64 + l];
    m = fmaxf(m, v[c]);
  }
#pragma unroll
  for (int off = 32; off; off >>= 1) m = fmaxf(m, __shfl_xor(m, off));
  float carry = 0.f;
  for (int c = 0; c < 8; c++) {
    float e = expf(v[c] - m);
    float s = e;
#pragma unroll
    for (int off = 1; off < 64; off <<= 1) {
      float u = __shfl_up(s, off);
      if (l >= off) s += u;
    }
    E[(size_t)br * T_ + c * 64 + l] = e;
    invd[(size_t)br * T_ + c * 64 + l] = 1.f / (carry + s);
    carry += __shfl(s, 63);
  }
}

// ---------------------------------------------------------------------------
// K3a: per (b, chunk): P[b][c][r][i] = sum_{t in chunk} E[b,r,t] * x[b,t,i]
// ---------------------------------------------------------------------------
__global__ __launch_bounds__(128) void k3a(const float* __restrict__ x,
                                           const float* __restrict__ E,
                                           float* __restrict__ P) {
  int b = blockIdx.x >> 3, c = blockIdx.x & 7;
  int i = threadIdx.x;
  int t0 = c * 64;
  __shared__ float es[2][R_];
  float acc[R_];
#pragma unroll
  for (int r = 0; r < R_; r++) acc[r] = 0.f;
  float rE = 0.f;
  if (i < R_) rE = E[((size_t)(b * R_ + i)) * T_ + t0];
  const float* xb = x + (size_t)b * T_ * I_;
  float xv = xb[(size_t)t0 * I_ + i];
  int buf = 0;
  for (int tt = 0; tt < 64; tt++) {
    if (i < R_) es[buf][i] = rE;
    __syncthreads();
    if (tt + 1 < 64) {
      if (i < R_) rE = E[((size_t)(b * R_ + i)) * T_ + t0 + tt + 1];
    }
    float xcur = xv;
    if (tt + 1 < 64) xv = xb[(size_t)(t0 + tt + 1) * I_ + i];
#pragma unroll
    for (int r = 0; r < R_; r++) acc[r] += es[buf][r] * xcur;
    buf ^= 1;
  }
#pragma unroll
  for (int r = 0; r < R_; r++)
    P[(size_t)((b * 8 + c) * R_ + r) * I_ + i] = acc[r];
}

// ---------------------------------------------------------------------------
// K3b: exclusive prefix of P over chunks, per (b,r,i). In place.
// ---------------------------------------------------------------------------
__global__ __launch_bounds__(256) void k3b(float* __restrict__ P) {
  int gid = blockIdx.x * 256 + threadIdx.x;
  int i = gid & 127;
  int r = (gid >> 7) % R_;
  int b = gid / (R_ * I_);
  float s = 0.f;
#pragma unroll
  for (int c = 0; c < 8; c++) {
    size_t idx = (size_t)((b * 8 + c) * R_ + r) * I_ + i;
    float v = P[idx];
    P[idx] = s;
    s += v;
  }
}

// ---------------------------------------------------------------------------
// K3c: per (b, chunk): acc init from P prefix, then 64 steps producing M.
// ---------------------------------------------------------------------------
__global__ __launch_bounds__(128) void k3c(const float* __restrict__ x,
                                           const float* __restrict__ E,
                                           const float* __restrict__ invd,
                                           const float* __restrict__ P,
                                           float* __restrict__ M) {
  int b = blockIdx.x >> 3, c = blockIdx.x & 7;
  int i = threadIdx.x;
  int t0 = c * 64;
  __shared__ float es[2][R_], ds[2][R_];
  float acc[R_];
#pragma unroll
  for (int r = 0; r < R_; r++)
    acc[r] = P[(size_t)((b * 8 + c) * R_ + r) * I_ + i];
  float rE = 0.f, rD = 0.f;
  if (i < R_)
    rE = E[((size_t)(b * R_ + i)) * T_ + t0];
  else if (i < 2 * R_)
    rD = invd[((size_t)(b * R_ + (i - R_))) * T_ + t0];
  const float* xb = x + (size_t)b * T_ * I_;
  float xv = xb[(size_t)t0 * I_ + i];
  int buf = 0;
  for (int tt = 0; tt < 64; tt++) {
    if (i < R_) es[buf][i] = rE;
    else if (i < 2 * R_) ds[buf][i - R_] = rD;
    __syncthreads();
    if (tt + 1 < 64) {
      if (i < R_)
        rE = E[((size_t)(b * R_ + i)) * T_ + t0 + tt + 1];
      else if (i < 2 * R_)
        rD = invd[((size_t)(b * R_ + (i - R_))) * T_ + t0 + tt + 1];
    }
    float xcur = xv;
    if (tt + 1 < 64) xv = xb[(size_t)(t0 + tt + 1) * I_ + i];
    float s = 0.f;
#pragma unroll
    for (int r = 0; r < R_; r++) {
      acc[r] += es[buf][r] * xcur;
      s += acc[r] * ds[buf][r];
    }
    M[(size_t)b * T_ * I_ + (size_t)(t0 + tt) * I_ + i] = s * (1.0f / R_);
    buf ^= 1;
  }
}

// ---------------------------------------------------------------------------
// K4: gx[row][g] = M[row,:] @ W_ih[:,g] + b[g].  Output fp16.
// ---------------------------------------------------------------------------
__global__ __launch_bounds__(256) void k4_gemm(const float* __restrict__ Mm,
                                               const float* __restrict__ Wih,
                                               const float* __restrict__ bg,
                                               __half* __restrict__ gx) {
  __shared__ float As[I_][64];
  __shared__ float Bs[I_][64];
  int row0 = blockIdx.x * 64, col0 = blockIdx.y * 64;
  int tid = threadIdx.x;
#pragma unroll
  for (int ch = 0; ch < 8; ch++) {
    int fidx = ch * 256 + tid;
    int r = fidx >> 5;
    int kk = (fidx & 31) << 2;
    float4 f = ((const float4*)(Mm + (size_t)(row0 + r) * I_))[fidx & 31];
    As[kk + 0][r] = f.x;
    As[kk + 1][r] = f.y;
    As[kk + 2][r] = f.z;
    As[kk + 3][r] = f.w;
  }
#pragma unroll
  for (int ch = 0; ch < 8; ch++) {
    int fidx = ch * 256 + tid;
    int k = fidx >> 4;
    int c4 = (fidx & 15) << 2;
    float4 f = *((const float4*)(Wih + (size_t)k * G4_ + col0 + c4));
    *((float4*)&Bs[k][c4]) = f;
  }
  __syncthreads();
  int ty = tid >> 4, tx = tid & 15;
  float acc[4][4] = {};
#pragma unroll 4
  for (int k = 0; k < I_; k++) {
    float4 a = *((float4*)&As[k][ty << 2]);
    float4 bq = *((float4*)&Bs[k][tx << 2]);
    acc[0][0] += a.x * bq.x; acc[0][1] += a.x * bq.y; acc[0][2] += a.x * bq.z; acc[0][3] += a.x * bq.w;
    acc[1][0] += a.y * bq.x; acc[1][1] += a.y * bq.y; acc[1][2] += a.y * bq.z; acc[1][3] += a.y * bq.w;
    acc[2][0] += a.z * bq.x; acc[2][1] += a.z * bq.y; acc[2][2] += a.z * bq.z; acc[2][3] += a.z * bq.w;
    acc[3][0] += a.w * bq.x; acc[3][1] += a.w * bq.y; acc[3][2] += a.w * bq.z; acc[3][3] += a.w * bq.w;
  }
#pragma unroll
  for (int ii = 0; ii < 4; ii++) {
#pragma unroll
    for (int jj = 0; jj < 4; jj++) {
      int row = row0 + (ty << 2) + ii;
      int col = col0 + (tx << 2) + jj;
      gx[(size_t)row * G4_ + col] = __float2half(acc[ii][jj] + bg[col]);
    }
  }
}

// ---------------------------------------------------------------------------
// K5: LSTM scan, k-split + batch-pair design (round-7 structure, FIXED swizzle).
// Grid 256 x 1024 (1 block/CU). Block = (partition p in 0..7 owning units
// p*32..p*32+31) x (batch-pair q in 0..31: b = 2q, 2q+1).
// Thread (u in 32, k16 in 16, bsub in 2): holds W for ALL 4 gates of its
// unit restricted to k-chunk [k16*16, k16*16+16) = 8 uint4 = 32 VGPRs.
// 32 W VGPRs + ~40 working < the ~88-VGPR ceiling the allocator enforced in
// rounds 0-6 -> no pressure -> no remat/spill of W (the failure mode that
// kept k5 L2-bound at ~56 B/cyc/CU in every prior round).
// h in LDS double-buffer, 16B-granule XOR swizzle (bijective, in-bounds):
//   granule g in [0,64) -> byte ((g ^ ((g>>3)&7)) << 4)
// spreads the wave's 32 read granules over all 8 bank-groups (4-way max).
// h exchange: u32 {step-tag<<16 | fp16} relaxed agent atomics; 8 partition
// blocks of a batch-pair co-located per XCD (bid%8 = q%8).
// ONE __syncthreads per step.
// ---------------------------------------------------------------------------
#define BCH2(u) __builtin_bit_cast(half2_t, (u))
#define FD(w, h, a) __builtin_amdgcn_fdot2(BCH2(w), BCH2(h), (a), false)

__device__ __forceinline__ int swzb(int g) {   // 16B-granule -> byte offset
  return (g ^ ((g >> 3) & 7)) << 4;
}

__global__ __launch_bounds__(1024, 4)
__attribute__((amdgpu_waves_per_eu(4, 4)))
void k5_lstm(const __half* __restrict__ gx, const half2_t* __restrict__ Wq,
             unsigned* __restrict__ Hx, float* __restrict__ hT) {
  int p = blockIdx.x >> 5;          // partition 0..7
  int q = blockIdx.x & 31;          // batch-pair
  int tid = threadIdx.x;
  int lane = tid & 63;
  int u_loc = tid >> 5;             // unit within partition 0..31
  int k16 = (tid >> 1) & 15;        // k-chunk 0..15
  int bsub = tid & 1;
  int u_glob = p * 32 + u_loc;      // global unit 0..255
  int b_glob = q * 2 + bsub;        // global batch

  // h double-buffer: 32 slots x 32 B (slot s = k16*2+bsub holds
  // h[batch bsub][k16*16 .. +16]); granule-swizzled addressing via swzb.
  __shared__ __align__(16) unsigned char hbuf[2][1024];

  // W: 8 uint4 = 32 VGPRs (column g stride 512 B; gate stride 131072 B).
  const unsigned char* wb =
      (const unsigned char*)Wq + (size_t)u_glob * 512 + k16 * 32;
  uint4 w0a = *(const uint4*)(wb);
  uint4 w0b = *(const uint4*)(wb + 16);
  uint4 w1a = *(const uint4*)(wb + 131072);
  uint4 w1b = *(const uint4*)(wb + 131072 + 16);
  uint4 w2a = *(const uint4*)(wb + 262144);
  uint4 w2b = *(const uint4*)(wb + 262144 + 16);
  uint4 w3a = *(const uint4*)(wb + 393216);
  uint4 w3b = *(const uint4*)(wb + 393216 + 16);

  // h0 = 1.0 everywhere (swizzle-agnostic fill)
  if (tid < 64)
    ((uint4*)hbuf[0])[tid] =
        make_uint4(0x3C003C00u, 0x3C003C00u, 0x3C003C00u, 0x3C003C00u);

  bool leader = (lane & 30) == 0;   // k16 == 0 lanes: {0,1,32,33} per wave
  float cstate = 1.0f;

  const __half* gxb = gx + (size_t)b_glob * T_ * G4_ + u_glob;
  float gx0 = 0.f, gx1 = 0.f, gx2 = 0.f, gx3 = 0.f;
  if (leader) {
    gx0 = (float)gxb[0];
    gx1 = (float)gxb[256];
    gx2 = (float)gxb[512];
    gx3 = (float)gxb[768];
  }

  // own h-read granules (slot rs = k16*2+bsub -> granules 2rs, 2rs+1)
  int rs = k16 * 2 + bsub;
  int ra0 = swzb(rs * 2);
  int ra1 = swzb(rs * 2 + 1);

  // poller mapping: tid<448 polls one remote packet (partition prt, unit uu,
  // batch bb) and scatters it into the swizzled LDS position.
  int pi = tid >> 6;
  int prt = pi + (pi >= p ? 1 : 0);
  int uu = (tid & 63) >> 1;
  int bb = tid & 1;
  int wss = (prt * 2 + (uu >> 4)) * 2 + bb;          // slot
  int wg = wss * 2 + ((uu >> 3) & 1);                // granule
  int ws_off = swzb(wg) + (uu & 7) * 2;              // byte

  // leader own-write position
  int os = (p * 2 + (u_loc >> 4)) * 2 + bsub;
  int og = os * 2 + ((u_loc >> 3) & 1);
  int oa = swzb(og) + (u_loc & 7) * 2;

  for (int t = 0; t < T_; t++) {
    // prefetch next step's gate inputs (leaders)
    float ng0 = 0.f, ng1 = 0.f, ng2 = 0.f, ng3 = 0.f;
    if (leader && t + 1 < T_) {
      const __half* gxt = gxb + (size_t)(t + 1) * G4_;
      ng0 = (float)gxt[0];
      ng1 = (float)gxt[256];
      ng2 = (float)gxt[512];
      ng3 = (float)gxt[768];
    }

    // poll remote partitions' h packets (448 pollers, 1 packet each)
    if (t > 0 && tid < 448) {
      const unsigned* src =
          Hx + (t & 1) * 16384 + (q * 2 + bb) * 256 + prt * 32 + uu;
      unsigned v;
      do {
        v = __hip_atomic_load(src, __ATOMIC_RELAXED, __HIP_MEMORY_SCOPE_AGENT);
      } while ((v >> 16) != (unsigned)t);
      *(unsigned short*)(hbuf[t & 1] + ws_off) = (unsigned short)(v & 0xffffu);
    }
    __syncthreads();   // orders h-writes (prev leaders + pollers) vs reads

    // 32B h chunk: two granule-swizzled b128 reads
    const unsigned char* hb = hbuf[t & 1];
    uint4 h0 = *(const uint4*)(hb + ra0);
    uint4 h1 = *(const uint4*)(hb + ra1);

    float a0 = 0.f, a1 = 0.f, a2 = 0.f, a3 = 0.f;
    a0 = FD(w0a.x, h0.x, a0); a0 = FD(w0a.y, h0.y, a0);
    a0 = FD(w0a.z, h0.z, a0); a0 = FD(w0a.w, h0.w, a0);
    a0 = FD(w0b.x, h1.x, a0); a0 = FD(w0b.y, h1.y, a0);
    a0 = FD(w0b.z, h1.z, a0); a0 = FD(w0b.w, h1.w, a0);
    a1 = FD(w1a.x, h0.x, a1); a1 = FD(w1a.y, h0.y, a1);
    a1 = FD(w1a.z, h0.z, a1); a1 = FD(w1a.w, h0.w, a1);
    a1 = FD(w1b.x, h1.x, a1); a1 = FD(w1b.y, h1.y, a1);
    a1 = FD(w1b.z, h1.z, a1); a1 = FD(w1b.w, h1.w, a1);
    a2 = FD(w2a.x, h0.x, a2); a2 = FD(w2a.y, h0.y, a2);
    a2 = FD(w2a.z, h0.z, a2); a2 = FD(w2a.w, h0.w, a2);
    a2 = FD(w2b.x, h1.x, a2); a2 = FD(w2b.y, h1.y, a2);
    a2 = FD(w2b.z, h1.z, a2); a2 = FD(w2b.w, h1.w, a2);
    a3 = FD(w3a.x, h0.x, a3); a3 = FD(w3a.y, h0.y, a3);
    a3 = FD(w3a.z, h0.z, a3); a3 = FD(w3a.w, h0.w, a3);
    a3 = FD(w3b.x, h1.x, a3); a3 = FD(w3b.y, h1.y, a3);
    a3 = FD(w3b.z, h1.z, a3); a3 = FD(w3b.w, h1.w, a3);

    // k-reduce over 16 chunks (lane bits 1..4)
#pragma unroll
    for (int off = 2; off <= 16; off <<= 1) {
      a0 += __shfl_xor(a0, off);
      a1 += __shfl_xor(a1, off);
      a2 += __shfl_xor(a2, off);
      a3 += __shfl_xor(a3, off);
    }

    if (leader) {
      float vi = fsigmoid(a0 + gx0);
      float vf = fsigmoid(a1 + gx1);
      float vg = ftanh(a2 + gx2);
      float vo = fsigmoid(a3 + gx3);
      cstate = vf * cstate + vi * vg;
      float h = vo * ftanh(cstate);
      unsigned h16 = (unsigned)__half_as_ushort(__float2half(h));
      if (t + 1 < T_) {
        unsigned pkt = ((unsigned)(t + 1) << 16) | h16;
        unsigned* dst = Hx + ((t + 1) & 1) * 16384 + b_glob * 256 + u_glob;
        __hip_atomic_store(dst, pkt, __ATOMIC_RELAXED, __HIP_MEMORY_SCOPE_AGENT);
        *(unsigned short*)(hbuf[(t + 1) & 1] + oa) = (unsigned short)h16;
      } else {
        hT[b_glob * H_ + u_glob] = h;
      }
    }
    gx0 = ng0; gx1 = ng1; gx2 = ng2; gx3 = ng3;
    // no second barrier: end-of-step writes target the other hbuf and a
    // fresh mailbox generation; next step's __syncthreads orders them.
  }
}

// ---------------------------------------------------------------------------
// K6: logits = hT @ Wfc^T + bfc; softmax.  One wave per b.
// ---------------------------------------------------------------------------
__global__ __launch_bounds__(64) void k6_head(const float* __restrict__ hT,
                                              const float* __restrict__ Wfc,
                                              const float* __restrict__ bfc,
                                              float* __restrict__ out) {
  int b = blockIdx.x, l = threadIdx.x;
  const float* h = hT + b * H_;
  float p[C_];
#pragma unroll
  for (int c = 0; c < C_; c++) p[c] = 0.f;
#pragma unroll
  for (int qq = 0; qq < 4; qq++) {
    float hv = h[qq * 64 + l];
#pragma unroll
    for (int c = 0; c < C_; c++) p[c] += hv * Wfc[c * H_ + qq * 64 + l];
  }
#pragma unroll
  for (int c = 0; c < C_; c++)
    for (int off = 32; off; off >>= 1) p[c] += __shfl_xor(p[c], off);
  if (l == 0) {
    float m = -1e30f, e[C_], sum = 0.f;
    for (int c = 0; c < C_; c++) { p[c] += bfc[c]; m = fmaxf(m, p[c]); }
    for (int c = 0; c < C_; c++) { e[c] = expf(p[c] - m); sum += e[c]; }
    for (int c = 0; c < C_; c++) out[b * C_ + c] = e[c] / sum;
  }
}

// ---------------------------------------------------------------------------
// Workspace layout (float offsets):
//   Hx    [2][64][256] u32 = dwords [0, 32768)   (aliases S; S dead after k2)
//   S     [B,R,T]        wsf + 0
//   E     [B,R,T]        wsf + 655360
//   INVD  [B,R,T]        wsf + 1310720
//   M     [B,T,I]        wsf + 1966080
//   hT    [B,H]          wsf + 6160384
//   Wq    [1024][128]h2  wsf + 6176768  (131072 dwords)
//   gx    [B,T,4H] fp16  wsf + 6307840  (16777216 dwords)
//   P     [B][8][R][I]   aliases gx region (P dead before k4 writes gx)
// ---------------------------------------------------------------------------
extern "C" void kernel_launch(void* const* d_in, const int* in_sizes, int n_in,
                              void* d_out, int out_size, void* d_ws, size_t ws_size,
                              hipStream_t stream) {
  const float* x   = (const float*)d_in[0];
  const float* Wih = (const float*)d_in[1];
  const float* Whh = (const float*)d_in[2];
  const float* bg  = (const float*)d_in[3];
  const float* W1  = (const float*)d_in[4];
  const float* b1  = (const float*)d_in[5];
  const float* W2  = (const float*)d_in[6];
  const float* b2  = (const float*)d_in[7];
  const float* Wfc = (const float*)d_in[8];
  const float* bfc = (const float*)d_in[9];
  float* out = (float*)d_out;

  float* wsf = (float*)d_ws;
  unsigned long long* Hx64 = (unsigned long long*)wsf;
  unsigned* Hx = (unsigned*)wsf;
  float* S    = wsf;
  float* E    = wsf + 655360;
  float* INVD = wsf + 1310720;
  float* Mm   = wsf + 1966080;
  float* hT   = wsf + 6160384;
  half2_t* Wq = (half2_t*)(wsf + 6176768);
  __half* gx  = (__half*)(wsf + 6307840);
  float* P    = wsf + 6307840;           // aliases gx region (disjoint in time)

  hipLaunchKernelGGL(k0_pack,   dim3(512),     dim3(256),  0, stream, Whh, Wq);
  hipLaunchKernelGGL(k1_scores, dim3(512),     dim3(256),  0, stream, x, W1, b1, W2, b2, S);
  hipLaunchKernelGGL(k2_prefix, dim3(B_ * R_), dim3(64),   0, stream, S, E, INVD);
  hipLaunchKernelGGL(k3a,       dim3(512),     dim3(128),  0, stream, x, E, P);
  hipLaunchKernelGGL(k3b,       dim3(640),     dim3(256),  0, stream, P);
  hipLaunchKernelGGL(k3c,       dim3(512),     dim3(128),  0, stream, x, E, INVD, P, Mm);
  hipLaunchKernelGGL(k4_gemm,   dim3(512, 16), dim3(256),  0, stream, Mm, Wih, bg, gx);
  hipLaunchKernelGGL(k_init,    dim3(64),      dim3(256),  0, stream, Hx64);
  hipLaunchKernelGGL(k5_lstm,   dim3(256),     dim3(1024), 0, stream, gx, Wq, Hx, hT);
  hipLaunchKernelGGL(k6_head,   dim3(B_),      dim3(64),   0, stream, hT, Wfc, bfc, out);
}